// Round 8
// baseline (252.423 us; speedup 1.0000x reference)
//
#include <hip/hip_runtime.h>
#include <hip/hip_bf16.h>
#include <math.h>
#include <type_traits>

// Problem constants (fixed by setup_inputs)
#define BATCH 8
#define QLEN 900
#define HEADS 8
#define LEVELS 4
#define POINTS 4
#define NUM_KEYS 13294
#define BQ (BATCH * QLEN)          // 7200
#define MROWS_V (BATCH * NUM_KEYS) // 106352
#define VTILES (MROWS_V / 16)      // 6647 16-row tiles (exact)
#define VBLOCKS 512
#define TPB 13                     // ceil(6647/512)

__constant__ const int c_LH[4] = {100, 50, 25, 13};
__constant__ const int c_LW[4] = {100, 50, 25, 13};
__constant__ const int c_LS[4] = {0, 10000, 12500, 13125};

typedef __attribute__((ext_vector_type(8))) short bfrag;   // 8 bf16
typedef __attribute__((ext_vector_type(4))) float ffrag;   // 4 fp32 acc

static __device__ __forceinline__ unsigned short f2bf(float f) {
    __hip_bfloat16 h = __float2bfloat16(f);
    return *(unsigned short*)&h;
}
static __device__ __forceinline__ float bf2f(unsigned int u16) {
    unsigned int v = u16 << 16;
    float f;
    __builtin_memcpy(&f, &v, 4);
    return f;
}
static __device__ __forceinline__ unsigned long long pack4bf(float4 v) {
    return (unsigned long long)f2bf(v.x)
         | ((unsigned long long)f2bf(v.y) << 16)
         | ((unsigned long long)f2bf(v.z) << 32)
         | ((unsigned long long)f2bf(v.w) << 48);
}

// ---------------------------------------------------------------------------
// Merged prep: cast+transpose all three weight matrices to bf16 [n][k],
// concat off/attn biases. One launch instead of five.
// ---------------------------------------------------------------------------
__global__ __launch_bounds__(256)
void prep_kernel(const float* __restrict__ W_val, const float* __restrict__ W_off,
                 const float* __restrict__ W_attn, const float* __restrict__ W_out,
                 const float* __restrict__ b_off, const float* __restrict__ b_attn,
                 unsigned short* __restrict__ Wv, unsigned short* __restrict__ Woa,
                 unsigned short* __restrict__ Wo, float* __restrict__ boa) {
    const int id = blockIdx.x * 256 + threadIdx.x;
    if (id < 65536) {
        const int n = id >> 8, k = id & 255;
        Wv[id] = f2bf(W_val[k * 256 + n]);
    } else if (id < 131072) {
        const int t = id - 65536;
        const int n = t >> 8, k = t & 255;
        Woa[t] = f2bf(W_off[k * 256 + n]);
    } else if (id < 163840) {
        const int t = id - 131072;
        const int n = t >> 8, k = t & 255;       // n in 0..127
        Woa[65536 + t] = f2bf(W_attn[k * 128 + n]);
    } else if (id < 229376) {
        const int t = id - 163840;
        const int n = t >> 8, k = t & 255;
        Wo[t] = f2bf(W_out[k * 256 + n]);
    } else if (id < 229760) {
        const int t = id - 229376;
        boa[t] = (t < 256) ? b_off[t] : b_attn[t - 256];
    }
}

// ---------------------------------------------------------------------------
// Value-projection GEMM v7: C = bf16(A @ Wv + bias), HEAD-MAJOR output
// [b][h][key][32]. 512 thr / 8 waves x 32 cols, b[2][8]=64 VGPR/wave,
// __launch_bounds__(512,4). Per-instruction-contiguous staging loads,
// f32->bf16 once at staging, 3-deep 8KB LDS ring, named L0/L1 reg sets
// (rule #20), one raw s_barrier + lgkmcnt(0) per tile, XOR-swizzled LDS.
// ---------------------------------------------------------------------------
#define VSTEP(T, LREG)                                                        \
  do {                                                                        \
    const char* abuf = (const char*)&Abuf[0][0] + rb * 8192;                  \
    ffrag acc[2];                                                             \
    _Pragma("unroll")                                                         \
    for (int j_ = 0; j_ < 2; ++j_) acc[j_] = (ffrag){0.f, 0.f, 0.f, 0.f};     \
    _Pragma("unroll")                                                         \
    for (int ks_ = 0; ks_ < 8; ++ks_) {                                       \
      const int ub_ = (ks_ * 64 + quad * 16) ^ ((ln & 7) << 4);               \
      const bfrag af_ = *(const bfrag*)(abuf + ln * 512 + ub_);               \
      _Pragma("unroll")                                                       \
      for (int j_ = 0; j_ < 2; ++j_)                                          \
        acc[j_] = __builtin_amdgcn_mfma_f32_16x16x32_bf16(af_, b[j_][ks_],    \
                                                          acc[j_], 0, 0, 0); \
    }                                                                         \
    if ((T) + 1 < t1) {                                                       \
      const int wb_ = (rb + 1 == 3) ? 0 : rb + 1;                             \
      char* dbuf_ = (char*)&Abuf[0][0] + wb_ * 8192;                          \
      _Pragma("unroll")                                                       \
      for (int i_ = 0; i_ < 2; ++i_)                                          \
        *(unsigned long long*)(dbuf_ + dsoff[i_]) = pack4bf(LREG[i_]);        \
      if ((T) + 3 < t1) {                                                     \
        const float4* ap_ = Af4 + (size_t)((T) + 3) * 1024 + tid;             \
        _Pragma("unroll")                                                     \
        for (int i_ = 0; i_ < 2; ++i_) LREG[i_] = ap_[i_ * 512];              \
      }                                                                       \
    }                                                                         \
    const int rowb_ = (T) * 16 + quad * 4;                                    \
    _Pragma("unroll")                                                         \
    for (int r_ = 0; r_ < 4; ++r_) {                                          \
      const unsigned row_ = rowb_ + r_;                                       \
      const unsigned bb_ = row_ / NUM_KEYS;                                   \
      const unsigned key_ = row_ - bb_ * NUM_KEYS;                            \
      _Pragma("unroll")                                                       \
      for (int j_ = 0; j_ < 2; ++j_) {                                        \
        const int col_ = n0 + j_ * 16 + ln;                                   \
        const int h_ = col_ >> 5, d_ = col_ & 31;                             \
        C[((size_t)(bb_ * 8 + h_) * NUM_KEYS + key_) * 32 + d_] =             \
            f2bf(acc[j_][r_] + bj[j_]);                                       \
      }                                                                       \
    }                                                                         \
    asm volatile("s_waitcnt lgkmcnt(0)" ::: "memory");                        \
    __builtin_amdgcn_s_barrier();                                             \
    rb = (rb + 1 == 3) ? 0 : rb + 1;                                          \
  } while (0)

__global__ __launch_bounds__(512, 4)
void gemm_val_stream(const float* __restrict__ A, const unsigned short* __restrict__ WT,
                     const float* __restrict__ bias, unsigned short* __restrict__ C) {
    __shared__ __align__(16) unsigned short Abuf[3][16 * 256];  // 3 x 8KB bf16 tiles
    const int tid = threadIdx.x;
    const int wave = tid >> 6;
    const int lane = tid & 63;
    const int ln = lane & 15;
    const int quad = lane >> 4;
    const int n0 = wave * 32;           // wave covers one 32-col head slice

    // persistent B fragments: 2 n-tiles x 8 k-steps (64 VGPR)
    bfrag b[2][8];
#pragma unroll
    for (int j = 0; j < 2; ++j) {
        const unsigned short* bp = WT + (size_t)(n0 + j * 16 + ln) * 256 + quad * 8;
#pragma unroll
        for (int ks = 0; ks < 8; ++ks) b[j][ks] = *(const bfrag*)(bp + ks * 32);
    }
    float bj[2];
#pragma unroll
    for (int j = 0; j < 2; ++j) bj[j] = bias[n0 + j * 16 + ln];

    const int t0 = blockIdx.x * TPB;
    const int t1 = min(t0 + TPB, VTILES);
    if (t0 >= t1) return;

    // staging destination offsets: instr i covers float4 index f = i*512+tid
    int dsoff[2];
#pragma unroll
    for (int i = 0; i < 2; ++i) {
        const int f = i * 512 + tid;
        const int r = f >> 6;
        const int cb = (f & 63) * 8;
        dsoff[i] = r * 512 + (cb ^ ((r & 7) << 4));
    }

    const float4* Af4 = (const float4*)A;

    // prologue: stage tile t0 directly, then fill the 2-deep NAMED register
    // pipeline: t0+1 -> L0, t0+2 -> L1.
    float4 L0[2], L1[2];
    {
        const float4* ap = Af4 + (size_t)t0 * 1024 + tid;
        float4 P[2];
#pragma unroll
        for (int i = 0; i < 2; ++i) P[i] = ap[i * 512];
#pragma unroll
        for (int i = 0; i < 2; ++i)
            *(unsigned long long*)((char*)&Abuf[0][0] + dsoff[i]) = pack4bf(P[i]);
    }
    if (t0 + 1 < t1) {
        const float4* ap = Af4 + (size_t)(t0 + 1) * 1024 + tid;
#pragma unroll
        for (int i = 0; i < 2; ++i) L0[i] = ap[i * 512];
    }
    if (t0 + 2 < t1) {
        const float4* ap = Af4 + (size_t)(t0 + 2) * 1024 + tid;
#pragma unroll
        for (int i = 0; i < 2; ++i) L1[i] = ap[i * 512];
    }
    asm volatile("s_waitcnt lgkmcnt(0)" ::: "memory");
    __builtin_amdgcn_s_barrier();

    int rb = 0;
    int t = t0;
    while (t + 1 < t1) {
        VSTEP(t, L0);
        VSTEP(t + 1, L1);
        t += 2;
    }
    if (t < t1) VSTEP(t, L0);
}

// ---------------------------------------------------------------------------
// bf16-MFMA GEMM: C[M,N] = bf16(A[M,256]) @ WT^T + bias.
// WT is [N][256] bf16 (pre-transposed). BM=64, BN=128, BK=64, 256 thr = 4 waves.
// Used only for the offattn GEMM now (out-proj fused into msda).
// ---------------------------------------------------------------------------
#define GST 72

template <typename AT, typename CT>
__global__ __launch_bounds__(256)
void gemm_mfma(const AT* __restrict__ A, const unsigned short* __restrict__ WT,
               const float* __restrict__ bias, CT* __restrict__ C,
               int M, int ldc) {
    __shared__ unsigned short As[64 * GST];
    __shared__ unsigned short Bs[128 * GST];
    const int tid = threadIdx.x;
    const int wave = tid >> 6;
    const int lane = tid & 63;
    const int ln = lane & 15;
    const int quad = lane >> 4;
    const int m0 = blockIdx.x * 64;
    const int n0 = blockIdx.y * 128;

    ffrag acc[8];
#pragma unroll
    for (int j = 0; j < 8; ++j) acc[j] = (ffrag){0.f, 0.f, 0.f, 0.f};

    const int ar = tid >> 2;            // A row in tile (0..63)
    const int akc = (tid & 3) * 16;     // A k-chunk (16 elems)
    const int brow = tid >> 1;          // B col in tile (0..127)
    const int bkc = (tid & 1) * 32;     // B k-chunk (32 elems)
    const bool a_ok = (m0 + ar) < M;
    const AT* a_src = A + (size_t)(m0 + ar) * 256 + akc;
    const unsigned short* b_src = WT + (size_t)(n0 + brow) * 256 + bkc;

    for (int k0 = 0; k0 < 256; k0 += 64) {
        // ---- stage A (64 x 64, -> bf16) ----
        unsigned short* adst = &As[ar * GST + akc];
        if constexpr (std::is_same<AT, float>::value) {
            float4 f0, f1, f2, f3;
            if (a_ok) {
                const float4* p = (const float4*)(a_src + k0);
                f0 = p[0]; f1 = p[1]; f2 = p[2]; f3 = p[3];
            } else {
                f0 = make_float4(0.f, 0.f, 0.f, 0.f);
                f1 = f0; f2 = f0; f3 = f0;
            }
            float v[16] = {f0.x, f0.y, f0.z, f0.w, f1.x, f1.y, f1.z, f1.w,
                           f2.x, f2.y, f2.z, f2.w, f3.x, f3.y, f3.z, f3.w};
            unsigned short u[16];
#pragma unroll
            for (int i = 0; i < 16; ++i) u[i] = f2bf(v[i]);
            ((uint4*)adst)[0] = ((uint4*)u)[0];
            ((uint4*)adst)[1] = ((uint4*)u)[1];
        } else {
            uint4 u0, u1;
            if (a_ok) {
                const uint4* p = (const uint4*)(a_src + k0);
                u0 = p[0]; u1 = p[1];
            } else {
                u0 = make_uint4(0, 0, 0, 0);
                u1 = u0;
            }
            ((uint4*)adst)[0] = u0;
            ((uint4*)adst)[1] = u1;
        }
        // ---- stage B (128 cols x 64 k) ----
        {
            const uint4* src = (const uint4*)(b_src + k0);
            uint4* dst = (uint4*)&Bs[brow * GST + bkc];
#pragma unroll
            for (int i = 0; i < 4; ++i) dst[i] = src[i];
        }
        __syncthreads();

#pragma unroll
        for (int ks = 0; ks < 2; ++ks) {
            const int koff = ks * 32 + quad * 8;
            bfrag af = *(const bfrag*)&As[(wave * 16 + ln) * GST + koff];
#pragma unroll
            for (int j = 0; j < 8; ++j) {
                bfrag bf = *(const bfrag*)&Bs[(j * 16 + ln) * GST + koff];
                acc[j] = __builtin_amdgcn_mfma_f32_16x16x32_bf16(af, bf, acc[j], 0, 0, 0);
            }
        }
        __syncthreads();
    }

    // epilogue: row = m0 + wave*16 + quad*4 + r, col = n0 + j*16 + ln
#pragma unroll
    for (int j = 0; j < 8; ++j) {
        const int col = n0 + j * 16 + ln;
        const float bb = bias[col];
#pragma unroll
        for (int r = 0; r < 4; ++r) {
            const int row = m0 + wave * 16 + quad * 4 + r;
            if (row < M) {
                const float v = acc[j][r] + bb;
                if constexpr (std::is_same<CT, unsigned short>::value) {
                    C[(size_t)row * ldc + col] = f2bf(v);
                } else {
                    C[(size_t)row * ldc + col] = v;
                }
            }
        }
    }
}

// ---------------------------------------------------------------------------
// Fused softmax + locations + bilinear sampling + OUTPUT PROJECTION.
// vb layout [b][h][key][32] bf16. Block = 256 threads = 8 queries.
// Sampling: thread = (q = tid>>5, h, dp) owns 8 dims; point-loop unroll 2
// (8 uint4 in flight — round 5 showed 16 spills).
// Round-8: out-projection fused. Sampled features written bf16 to an LDS
// tile (16 rows: 8 real + 8 never-stored garbage rows; MFMA row independence
// makes zero-fill unnecessary), XOR-swizzled. Then the block's 4 waves each
// compute a 64-col strip of out = msda @ Wo^T + b_out (32 MFMAs/wave; Wo is
// 128KB, L2-resident). Removes: msda bf16 write, outproj kernel's staging
// read + full dispatch. Numerics identical to the standalone outproj GEMM.
// LDS: 4+4+4+8 = 20KB; launch_bounds(256,4) -> 4 blocks/CU, 80KB/CU.
// ---------------------------------------------------------------------------
__global__ __launch_bounds__(256, 4)
void msda_fused_kernel(const float* __restrict__ offattn,  // [BQ][384]
                       const float* __restrict__ rp,
                       const unsigned short* __restrict__ vb,  // [b][h][key][32] bf16
                       const unsigned short* __restrict__ Wo,  // [n][k] bf16
                       const float* __restrict__ b_out,
                       float* __restrict__ out) {              // [BQ][256] f32
    const int bq0 = blockIdx.x * 8;
    const int tid = threadIdx.x;

    __shared__ float s_w[8][128];
    __shared__ float s_x[8][128];
    __shared__ float s_y[8][128];
    __shared__ __align__(16) unsigned short s_o[16 * 256];  // 8 real + 8 pad rows

    // load attn logits (8 x 128) into s_w
#pragma unroll
    for (int i = 0; i < 4; ++i) {
        const int e = i * 256 + tid;
        const int q = e >> 7, t = e & 127;
        s_w[q][t] = offattn[(size_t)(bq0 + q) * 384 + 256 + t];
    }
    __syncthreads();

    // softmax per (q,h): 64 threads
    if (tid < 64) {
        const int q = tid >> 3, h = tid & 7;
        float m = -1e30f;
#pragma unroll
        for (int i = 0; i < 16; ++i) m = fmaxf(m, s_w[q][h * 16 + i]);
        float e[16];
        float s = 0.f;
#pragma unroll
        for (int i = 0; i < 16; ++i) {
            e[i] = expf(s_w[q][h * 16 + i] - m);
            s += e[i];
        }
        const float inv = 1.f / s;
#pragma unroll
        for (int i = 0; i < 16; ++i) s_w[q][h * 16 + i] = e[i] * inv;
    }

    // sampling coordinates (8 x 128)
#pragma unroll
    for (int i = 0; i < 4; ++i) {
        const int e = i * 256 + tid;
        const int q = e >> 7, t = e & 127;
        const int h = t >> 4, l = (t >> 2) & 3, p = t & 3;
        const int bq = bq0 + q;
        const float2 off = *(const float2*)(offattn + (size_t)bq * 384 + h * 32 + l * 8 + p * 2);
        const float Wl = (float)c_LW[l];
        const float Hl = (float)c_LH[l];
        const float rx = rp[((size_t)bq * 4 + l) * 2 + 0];
        const float ry = rp[((size_t)bq * 4 + l) * 2 + 1];
        s_x[q][t] = (rx + off.x / Wl) * Wl - 0.5f;   // reference op order
        s_y[q][t] = (ry + off.y / Hl) * Hl - 0.5f;
    }
    __syncthreads();

    const int q = tid >> 5;
    const int s = tid & 31;
    const int h = s >> 2;
    const int dp = s & 3;
    const int b = (bq0 + q) / QLEN;
    // head-major base: [b][h][key][32], thread reads 8 dims at dp*8
    const unsigned short* vbase = vb + (size_t)(b * 8 + h) * NUM_KEYS * 32 + dp * 8;

    float acc[8];
#pragma unroll
    for (int d = 0; d < 8; ++d) acc[d] = 0.f;

#pragma unroll
    for (int l = 0; l < LEVELS; ++l) {
        const int Hl = c_LH[l];
        const int Wl = c_LW[l];
        const int s0 = c_LS[l];
#pragma unroll 2
        for (int p = 0; p < POINTS; ++p) {
            const int t2 = h * 16 + l * 4 + p;
            const float x = s_x[q][t2];
            const float y = s_y[q][t2];
            const float w = s_w[q][t2];
            const float x0f = floorf(x);
            const float y0f = floorf(y);
            const float wx = x - x0f;
            const float wy = y - y0f;
            const int x0 = (int)x0f;
            const int y0 = (int)y0f;
            const float mx0 = ((unsigned)x0 < (unsigned)Wl) ? 1.f : 0.f;
            const float mx1 = ((unsigned)(x0 + 1) < (unsigned)Wl) ? 1.f : 0.f;
            const float my0 = ((unsigned)y0 < (unsigned)Hl) ? 1.f : 0.f;
            const float my1 = ((unsigned)(y0 + 1) < (unsigned)Hl) ? 1.f : 0.f;
            const int xc0 = min(max(x0, 0), Wl - 1);
            const int xc1 = min(max(x0 + 1, 0), Wl - 1);
            const int yc0 = min(max(y0, 0), Hl - 1);
            const int yc1 = min(max(y0 + 1, 0), Hl - 1);
            const float a00 = w * (1.f - wx) * (1.f - wy) * mx0 * my0;
            const float a01 = w * wx * (1.f - wy) * mx1 * my0;
            const float a10 = w * (1.f - wx) * wy * mx0 * my1;
            const float a11 = w * wx * wy * mx1 * my1;
            const size_t k00 = (size_t)(s0 + yc0 * Wl + xc0) * 32;
            const size_t k01 = (size_t)(s0 + yc0 * Wl + xc1) * 32;
            const size_t k10 = (size_t)(s0 + yc1 * Wl + xc0) * 32;
            const size_t k11 = (size_t)(s0 + yc1 * Wl + xc1) * 32;
            const uint4 r00 = *(const uint4*)(vbase + k00);
            const uint4 r01 = *(const uint4*)(vbase + k01);
            const uint4 r10 = *(const uint4*)(vbase + k10);
            const uint4 r11 = *(const uint4*)(vbase + k11);
            const unsigned int w00[4] = {r00.x, r00.y, r00.z, r00.w};
            const unsigned int w01[4] = {r01.x, r01.y, r01.z, r01.w};
            const unsigned int w10[4] = {r10.x, r10.y, r10.z, r10.w};
            const unsigned int w11[4] = {r11.x, r11.y, r11.z, r11.w};
#pragma unroll
            for (int i = 0; i < 4; ++i) {
                const float v00l = bf2f(w00[i] & 0xffffu), v00h = bf2f(w00[i] >> 16);
                const float v01l = bf2f(w01[i] & 0xffffu), v01h = bf2f(w01[i] >> 16);
                const float v10l = bf2f(w10[i] & 0xffffu), v10h = bf2f(w10[i] >> 16);
                const float v11l = bf2f(w11[i] & 0xffffu), v11h = bf2f(w11[i] >> 16);
                acc[i * 2 + 0] = fmaf(a00, v00l, fmaf(a01, v01l, fmaf(a10, v10l, fmaf(a11, v11l, acc[i * 2 + 0]))));
                acc[i * 2 + 1] = fmaf(a00, v00h, fmaf(a01, v01h, fmaf(a10, v10h, fmaf(a11, v11h, acc[i * 2 + 1]))));
            }
        }
    }

    // write sampled features to LDS (bf16, XOR-swizzled: byte(row,cb) =
    // row*512 + (cb ^ ((row&7)<<4)), same involution on write and read)
    {
        unsigned short o[8];
#pragma unroll
        for (int d = 0; d < 8; ++d) o[d] = f2bf(acc[d]);
        const int cb = (h * 32 + dp * 8) * 2;
        *(uint4*)((char*)s_o + q * 512 + (cb ^ ((q & 7) << 4))) = *(uint4*)o;
    }
    __syncthreads();

    // ---- fused output projection: out[8][256] = s_o[0:8] @ Wo^T + b_out ----
    // 4 waves x 64-col strips; rows 8..15 of s_o are garbage -> acc quads 2,3
    // discarded (MFMA row independence).
    {
        const int wv = tid >> 6;
        const int lane = tid & 63;
        const int ln = lane & 15;
        const int quad = lane >> 4;
        const int n0 = wv * 64;

        ffrag oacc[4];
#pragma unroll
        for (int j = 0; j < 4; ++j) oacc[j] = (ffrag){0.f, 0.f, 0.f, 0.f};
#pragma unroll
        for (int ks = 0; ks < 8; ++ks) {
            const int cbk = (ks * 64 + quad * 16) ^ ((ln & 7) << 4);
            const bfrag af = *(const bfrag*)((const char*)s_o + ln * 512 + cbk);
#pragma unroll
            for (int j = 0; j < 4; ++j) {
                const bfrag bf = *(const bfrag*)(Wo + (size_t)(n0 + j * 16 + ln) * 256 + ks * 32 + quad * 8);
                oacc[j] = __builtin_amdgcn_mfma_f32_16x16x32_bf16(af, bf, oacc[j], 0, 0, 0);
            }
        }
        // store rows 0..7 (quads 0,1): row = quad*4 + r, col = n0 + j*16 + ln
        if (quad < 2) {
#pragma unroll
            for (int j = 0; j < 4; ++j) {
                const int col = n0 + j * 16 + ln;
                const float bb = b_out[col];
#pragma unroll
                for (int r = 0; r < 4; ++r)
                    out[(size_t)(bq0 + quad * 4 + r) * 256 + col] = oacc[j][r] + bb;
            }
        }
    }
}

// ---------------------------------------------------------------------------
extern "C" void kernel_launch(void* const* d_in, const int* in_sizes, int n_in,
                              void* d_out, int out_size, void* d_ws, size_t ws_size,
                              hipStream_t stream) {
    const float* query  = (const float*)d_in[0];
    const float* rp     = (const float*)d_in[1];
    const float* value  = (const float*)d_in[2];
    const float* W_off  = (const float*)d_in[5];
    const float* b_off  = (const float*)d_in[6];
    const float* W_attn = (const float*)d_in[7];
    const float* b_attn = (const float*)d_in[8];
    const float* W_val  = (const float*)d_in[9];
    const float* b_val  = (const float*)d_in[10];
    const float* W_out  = (const float*)d_in[11];
    const float* b_out  = (const float*)d_in[12];
    float* out = (float*)d_out;

    // workspace layout
    char* w = (char*)d_ws;
    unsigned short* ws_vb = (unsigned short*)w;                 // [b][h][key][32] bf16
    w += (size_t)MROWS_V * 256 * 2;
    float* ws_offattn = (float*)w;                              // BQ*384 f32
    w += (size_t)BQ * 384 * 4;
    unsigned short* ws_msda = (unsigned short*)w;               // (unused, kept for layout)
    w += (size_t)BQ * 256 * 2;
    unsigned short* ws_Wv = (unsigned short*)w;  w += 256 * 256 * 2;   // [n][k]
    unsigned short* ws_Woa = (unsigned short*)w; w += 384 * 256 * 2;   // [n][k]
    unsigned short* ws_Wo = (unsigned short*)w;  w += 256 * 256 * 2;   // [n][k]
    float* ws_boa = (float*)w;                                   // 384 f32
    (void)ws_msda;

    // 0. merged weight prep (bf16, transposed) + bias concat
    prep_kernel<<<898, 256, 0, stream>>>(W_val, W_off, W_attn, W_out,
                                         b_off, b_attn, ws_Wv, ws_Woa, ws_Wo, ws_boa);

    // 1. value projection -> bf16 head-major (M=106352, N=256), 512-thr blocks
    gemm_val_stream<<<VBLOCKS, 512, 0, stream>>>(value, ws_Wv, b_val, ws_vb);

    // 2. fused offset+attn projection -> fp32 (M=7200, N=384)
    {
        dim3 grid((BQ + 63) / 64, 3);
        gemm_mfma<float, float><<<grid, 256, 0, stream>>>(
            query, ws_Woa, ws_boa, ws_offattn, BQ, 384);
    }
    // 3. softmax + locations + sampling + output projection -> d_out
    msda_fused_kernel<<<BQ / 8, 256, 0, stream>>>(ws_offattn, rp, ws_vb,
                                                  ws_Wo, b_out, out);
}

// Round 9
// 249.498 us; speedup vs baseline: 1.0117x; 1.0117x over previous
//
#include <hip/hip_runtime.h>
#include <hip/hip_bf16.h>
#include <math.h>
#include <type_traits>

// Problem constants (fixed by setup_inputs)
#define BATCH 8
#define QLEN 900
#define HEADS 8
#define LEVELS 4
#define POINTS 4
#define NUM_KEYS 13294
#define BQ (BATCH * QLEN)          // 7200
#define MROWS_V (BATCH * NUM_KEYS) // 106352
#define VTILES (MROWS_V / 16)      // 6647 16-row tiles (exact)
#define VBLOCKS 512
#define TPB 13                     // ceil(6647/512)

__constant__ const int c_LH[4] = {100, 50, 25, 13};
__constant__ const int c_LW[4] = {100, 50, 25, 13};
__constant__ const int c_LS[4] = {0, 10000, 12500, 13125};

typedef __attribute__((ext_vector_type(8))) short bfrag;   // 8 bf16
typedef __attribute__((ext_vector_type(4))) float ffrag;   // 4 fp32 acc

static __device__ __forceinline__ unsigned short f2bf(float f) {
    __hip_bfloat16 h = __float2bfloat16(f);
    return *(unsigned short*)&h;
}
static __device__ __forceinline__ float bf2f(unsigned int u16) {
    unsigned int v = u16 << 16;
    float f;
    __builtin_memcpy(&f, &v, 4);
    return f;
}
static __device__ __forceinline__ unsigned long long pack4bf(float4 v) {
    return (unsigned long long)f2bf(v.x)
         | ((unsigned long long)f2bf(v.y) << 16)
         | ((unsigned long long)f2bf(v.z) << 32)
         | ((unsigned long long)f2bf(v.w) << 48);
}

// ---------------------------------------------------------------------------
// Merged prep: cast+transpose all three weight matrices to bf16 [n][k],
// concat off/attn biases. One launch instead of five.
// ---------------------------------------------------------------------------
__global__ __launch_bounds__(256)
void prep_kernel(const float* __restrict__ W_val, const float* __restrict__ W_off,
                 const float* __restrict__ W_attn, const float* __restrict__ W_out,
                 const float* __restrict__ b_off, const float* __restrict__ b_attn,
                 unsigned short* __restrict__ Wv, unsigned short* __restrict__ Woa,
                 unsigned short* __restrict__ Wo, float* __restrict__ boa) {
    const int id = blockIdx.x * 256 + threadIdx.x;
    if (id < 65536) {
        const int n = id >> 8, k = id & 255;
        Wv[id] = f2bf(W_val[k * 256 + n]);
    } else if (id < 131072) {
        const int t = id - 65536;
        const int n = t >> 8, k = t & 255;
        Woa[t] = f2bf(W_off[k * 256 + n]);
    } else if (id < 163840) {
        const int t = id - 131072;
        const int n = t >> 8, k = t & 255;       // n in 0..127
        Woa[65536 + t] = f2bf(W_attn[k * 128 + n]);
    } else if (id < 229376) {
        const int t = id - 163840;
        const int n = t >> 8, k = t & 255;
        Wo[t] = f2bf(W_out[k * 256 + n]);
    } else if (id < 229760) {
        const int t = id - 229376;
        boa[t] = (t < 256) ? b_off[t] : b_attn[t - 256];
    }
}

// ---------------------------------------------------------------------------
// Value-projection GEMM v7: C = bf16(A @ Wv + bias), HEAD-MAJOR output
// [b][h][key][32]. 512 thr / 8 waves x 32 cols, b[2][8]=64 VGPR/wave,
// __launch_bounds__(512,4). Per-instruction-contiguous staging loads,
// f32->bf16 once at staging, 3-deep 8KB LDS ring, named L0/L1 reg sets
// (rule #20), one raw s_barrier + lgkmcnt(0) per tile, XOR-swizzled LDS.
// ---------------------------------------------------------------------------
#define VSTEP(T, LREG)                                                        \
  do {                                                                        \
    const char* abuf = (const char*)&Abuf[0][0] + rb * 8192;                  \
    ffrag acc[2];                                                             \
    _Pragma("unroll")                                                         \
    for (int j_ = 0; j_ < 2; ++j_) acc[j_] = (ffrag){0.f, 0.f, 0.f, 0.f};     \
    _Pragma("unroll")                                                         \
    for (int ks_ = 0; ks_ < 8; ++ks_) {                                       \
      const int ub_ = (ks_ * 64 + quad * 16) ^ ((ln & 7) << 4);               \
      const bfrag af_ = *(const bfrag*)(abuf + ln * 512 + ub_);               \
      _Pragma("unroll")                                                       \
      for (int j_ = 0; j_ < 2; ++j_)                                          \
        acc[j_] = __builtin_amdgcn_mfma_f32_16x16x32_bf16(af_, b[j_][ks_],    \
                                                          acc[j_], 0, 0, 0); \
    }                                                                         \
    if ((T) + 1 < t1) {                                                       \
      const int wb_ = (rb + 1 == 3) ? 0 : rb + 1;                             \
      char* dbuf_ = (char*)&Abuf[0][0] + wb_ * 8192;                          \
      _Pragma("unroll")                                                       \
      for (int i_ = 0; i_ < 2; ++i_)                                          \
        *(unsigned long long*)(dbuf_ + dsoff[i_]) = pack4bf(LREG[i_]);        \
      if ((T) + 3 < t1) {                                                     \
        const float4* ap_ = Af4 + (size_t)((T) + 3) * 1024 + tid;             \
        _Pragma("unroll")                                                     \
        for (int i_ = 0; i_ < 2; ++i_) LREG[i_] = ap_[i_ * 512];              \
      }                                                                       \
    }                                                                         \
    const int rowb_ = (T) * 16 + quad * 4;                                    \
    _Pragma("unroll")                                                         \
    for (int r_ = 0; r_ < 4; ++r_) {                                          \
      const unsigned row_ = rowb_ + r_;                                       \
      const unsigned bb_ = row_ / NUM_KEYS;                                   \
      const unsigned key_ = row_ - bb_ * NUM_KEYS;                            \
      _Pragma("unroll")                                                       \
      for (int j_ = 0; j_ < 2; ++j_) {                                        \
        const int col_ = n0 + j_ * 16 + ln;                                   \
        const int h_ = col_ >> 5, d_ = col_ & 31;                             \
        C[((size_t)(bb_ * 8 + h_) * NUM_KEYS + key_) * 32 + d_] =             \
            f2bf(acc[j_][r_] + bj[j_]);                                       \
      }                                                                       \
    }                                                                         \
    asm volatile("s_waitcnt lgkmcnt(0)" ::: "memory");                        \
    __builtin_amdgcn_s_barrier();                                             \
    rb = (rb + 1 == 3) ? 0 : rb + 1;                                          \
  } while (0)

__global__ __launch_bounds__(512, 4)
void gemm_val_stream(const float* __restrict__ A, const unsigned short* __restrict__ WT,
                     const float* __restrict__ bias, unsigned short* __restrict__ C) {
    __shared__ __align__(16) unsigned short Abuf[3][16 * 256];  // 3 x 8KB bf16 tiles
    const int tid = threadIdx.x;
    const int wave = tid >> 6;
    const int lane = tid & 63;
    const int ln = lane & 15;
    const int quad = lane >> 4;
    const int n0 = wave * 32;           // wave covers one 32-col head slice

    // persistent B fragments: 2 n-tiles x 8 k-steps (64 VGPR)
    bfrag b[2][8];
#pragma unroll
    for (int j = 0; j < 2; ++j) {
        const unsigned short* bp = WT + (size_t)(n0 + j * 16 + ln) * 256 + quad * 8;
#pragma unroll
        for (int ks = 0; ks < 8; ++ks) b[j][ks] = *(const bfrag*)(bp + ks * 32);
    }
    float bj[2];
#pragma unroll
    for (int j = 0; j < 2; ++j) bj[j] = bias[n0 + j * 16 + ln];

    const int t0 = blockIdx.x * TPB;
    const int t1 = min(t0 + TPB, VTILES);
    if (t0 >= t1) return;

    // staging destination offsets: instr i covers float4 index f = i*512+tid
    int dsoff[2];
#pragma unroll
    for (int i = 0; i < 2; ++i) {
        const int f = i * 512 + tid;
        const int r = f >> 6;
        const int cb = (f & 63) * 8;
        dsoff[i] = r * 512 + (cb ^ ((r & 7) << 4));
    }

    const float4* Af4 = (const float4*)A;

    // prologue: stage tile t0 directly, then fill the 2-deep NAMED register
    // pipeline: t0+1 -> L0, t0+2 -> L1.
    float4 L0[2], L1[2];
    {
        const float4* ap = Af4 + (size_t)t0 * 1024 + tid;
        float4 P[2];
#pragma unroll
        for (int i = 0; i < 2; ++i) P[i] = ap[i * 512];
#pragma unroll
        for (int i = 0; i < 2; ++i)
            *(unsigned long long*)((char*)&Abuf[0][0] + dsoff[i]) = pack4bf(P[i]);
    }
    if (t0 + 1 < t1) {
        const float4* ap = Af4 + (size_t)(t0 + 1) * 1024 + tid;
#pragma unroll
        for (int i = 0; i < 2; ++i) L0[i] = ap[i * 512];
    }
    if (t0 + 2 < t1) {
        const float4* ap = Af4 + (size_t)(t0 + 2) * 1024 + tid;
#pragma unroll
        for (int i = 0; i < 2; ++i) L1[i] = ap[i * 512];
    }
    asm volatile("s_waitcnt lgkmcnt(0)" ::: "memory");
    __builtin_amdgcn_s_barrier();

    int rb = 0;
    int t = t0;
    while (t + 1 < t1) {
        VSTEP(t, L0);
        VSTEP(t + 1, L1);
        t += 2;
    }
    if (t < t1) VSTEP(t, L0);
}

// ---------------------------------------------------------------------------
// bf16-MFMA GEMM: C[M,N] = bf16(A[M,256]) @ WT^T + bias.
// WT is [N][256] bf16 (pre-transposed). BM=64, BN=128, BK=64, 256 thr = 4 waves.
// Used only for the offattn GEMM now (out-proj fused into msda).
// ---------------------------------------------------------------------------
#define GST 72

template <typename AT, typename CT>
__global__ __launch_bounds__(256)
void gemm_mfma(const AT* __restrict__ A, const unsigned short* __restrict__ WT,
               const float* __restrict__ bias, CT* __restrict__ C,
               int M, int ldc) {
    __shared__ unsigned short As[64 * GST];
    __shared__ unsigned short Bs[128 * GST];
    const int tid = threadIdx.x;
    const int wave = tid >> 6;
    const int lane = tid & 63;
    const int ln = lane & 15;
    const int quad = lane >> 4;
    const int m0 = blockIdx.x * 64;
    const int n0 = blockIdx.y * 128;

    ffrag acc[8];
#pragma unroll
    for (int j = 0; j < 8; ++j) acc[j] = (ffrag){0.f, 0.f, 0.f, 0.f};

    const int ar = tid >> 2;            // A row in tile (0..63)
    const int akc = (tid & 3) * 16;     // A k-chunk (16 elems)
    const int brow = tid >> 1;          // B col in tile (0..127)
    const int bkc = (tid & 1) * 32;     // B k-chunk (32 elems)
    const bool a_ok = (m0 + ar) < M;
    const AT* a_src = A + (size_t)(m0 + ar) * 256 + akc;
    const unsigned short* b_src = WT + (size_t)(n0 + brow) * 256 + bkc;

    for (int k0 = 0; k0 < 256; k0 += 64) {
        // ---- stage A (64 x 64, -> bf16) ----
        unsigned short* adst = &As[ar * GST + akc];
        if constexpr (std::is_same<AT, float>::value) {
            float4 f0, f1, f2, f3;
            if (a_ok) {
                const float4* p = (const float4*)(a_src + k0);
                f0 = p[0]; f1 = p[1]; f2 = p[2]; f3 = p[3];
            } else {
                f0 = make_float4(0.f, 0.f, 0.f, 0.f);
                f1 = f0; f2 = f0; f3 = f0;
            }
            float v[16] = {f0.x, f0.y, f0.z, f0.w, f1.x, f1.y, f1.z, f1.w,
                           f2.x, f2.y, f2.z, f2.w, f3.x, f3.y, f3.z, f3.w};
            unsigned short u[16];
#pragma unroll
            for (int i = 0; i < 16; ++i) u[i] = f2bf(v[i]);
            ((uint4*)adst)[0] = ((uint4*)u)[0];
            ((uint4*)adst)[1] = ((uint4*)u)[1];
        } else {
            uint4 u0, u1;
            if (a_ok) {
                const uint4* p = (const uint4*)(a_src + k0);
                u0 = p[0]; u1 = p[1];
            } else {
                u0 = make_uint4(0, 0, 0, 0);
                u1 = u0;
            }
            ((uint4*)adst)[0] = u0;
            ((uint4*)adst)[1] = u1;
        }
        // ---- stage B (128 cols x 64 k) ----
        {
            const uint4* src = (const uint4*)(b_src + k0);
            uint4* dst = (uint4*)&Bs[brow * GST + bkc];
#pragma unroll
            for (int i = 0; i < 4; ++i) dst[i] = src[i];
        }
        __syncthreads();

#pragma unroll
        for (int ks = 0; ks < 2; ++ks) {
            const int koff = ks * 32 + quad * 8;
            bfrag af = *(const bfrag*)&As[(wave * 16 + ln) * GST + koff];
#pragma unroll
            for (int j = 0; j < 8; ++j) {
                bfrag bf = *(const bfrag*)&Bs[(j * 16 + ln) * GST + koff];
                acc[j] = __builtin_amdgcn_mfma_f32_16x16x32_bf16(af, bf, acc[j], 0, 0, 0);
            }
        }
        __syncthreads();
    }

    // epilogue: row = m0 + wave*16 + quad*4 + r, col = n0 + j*16 + ln
#pragma unroll
    for (int j = 0; j < 8; ++j) {
        const int col = n0 + j * 16 + ln;
        const float bb = bias[col];
#pragma unroll
        for (int r = 0; r < 4; ++r) {
            const int row = m0 + wave * 16 + quad * 4 + r;
            if (row < M) {
                const float v = acc[j][r] + bb;
                if constexpr (std::is_same<CT, unsigned short>::value) {
                    C[(size_t)row * ldc + col] = f2bf(v);
                } else {
                    C[(size_t)row * ldc + col] = v;
                }
            }
        }
    }
}

// ---------------------------------------------------------------------------
// Fused softmax + locations + bilinear sampling + OUTPUT PROJECTION.
// vb layout [b][h][key][32] bf16. Block = 256 threads = 8 queries.
// Round-9: bijective XCD-chunk swizzle on blockIdx (T1/m204). The full
// 900-block grid is co-resident (4 blocks/CU); default round-robin gives
// every XCD a uniform spread of bq over all 8 batches -> per-XCD gather
// working set = whole value tensor (54MB) vs 4MB L2 -> all gathers pay
// L3 latency. Swizzle gives each XCD one contiguous ~900-query range
// (~one batch): working set 6.8MB with ~4.4x intra-batch reuse -> most
// gathers become L2 hits. Zero numerics change.
// Sampling: thread = (q = tid>>5, h, dp) owns 8 dims; point-loop unroll 2
// (8 uint4 in flight — round 5 showed 16 spills). Outproj fused via 8KB
// XOR-swizzled LDS tile + 4 waves x 64-col strips of Wo (L2-resident).
// ---------------------------------------------------------------------------
__global__ __launch_bounds__(256, 4)
void msda_fused_kernel(const float* __restrict__ offattn,  // [BQ][384]
                       const float* __restrict__ rp,
                       const unsigned short* __restrict__ vb,  // [b][h][key][32] bf16
                       const unsigned short* __restrict__ Wo,  // [n][k] bf16
                       const float* __restrict__ b_out,
                       float* __restrict__ out) {              // [BQ][256] f32
    // bijective XCD-chunk swizzle: nwg=900, q=112, r=4 (m204).
    // XCD k (= orig%8) gets a contiguous wgid chunk -> contiguous bq range.
    const int orig = blockIdx.x;
    const int xcd = orig & 7;
    const int idx = orig >> 3;
    const int wgid = (xcd < 4) ? (xcd * 113 + idx) : (452 + (xcd - 4) * 112 + idx);
    const int bq0 = wgid * 8;
    const int tid = threadIdx.x;

    __shared__ float s_w[8][128];
    __shared__ float s_x[8][128];
    __shared__ float s_y[8][128];
    __shared__ __align__(16) unsigned short s_o[16 * 256];  // 8 real + 8 pad rows

    // load attn logits (8 x 128) into s_w
#pragma unroll
    for (int i = 0; i < 4; ++i) {
        const int e = i * 256 + tid;
        const int q = e >> 7, t = e & 127;
        s_w[q][t] = offattn[(size_t)(bq0 + q) * 384 + 256 + t];
    }
    __syncthreads();

    // softmax per (q,h): 64 threads
    if (tid < 64) {
        const int q = tid >> 3, h = tid & 7;
        float m = -1e30f;
#pragma unroll
        for (int i = 0; i < 16; ++i) m = fmaxf(m, s_w[q][h * 16 + i]);
        float e[16];
        float s = 0.f;
#pragma unroll
        for (int i = 0; i < 16; ++i) {
            e[i] = expf(s_w[q][h * 16 + i] - m);
            s += e[i];
        }
        const float inv = 1.f / s;
#pragma unroll
        for (int i = 0; i < 16; ++i) s_w[q][h * 16 + i] = e[i] * inv;
    }

    // sampling coordinates (8 x 128)
#pragma unroll
    for (int i = 0; i < 4; ++i) {
        const int e = i * 256 + tid;
        const int q = e >> 7, t = e & 127;
        const int h = t >> 4, l = (t >> 2) & 3, p = t & 3;
        const int bq = bq0 + q;
        const float2 off = *(const float2*)(offattn + (size_t)bq * 384 + h * 32 + l * 8 + p * 2);
        const float Wl = (float)c_LW[l];
        const float Hl = (float)c_LH[l];
        const float rx = rp[((size_t)bq * 4 + l) * 2 + 0];
        const float ry = rp[((size_t)bq * 4 + l) * 2 + 1];
        s_x[q][t] = (rx + off.x / Wl) * Wl - 0.5f;   // reference op order
        s_y[q][t] = (ry + off.y / Hl) * Hl - 0.5f;
    }
    __syncthreads();

    const int q = tid >> 5;
    const int s = tid & 31;
    const int h = s >> 2;
    const int dp = s & 3;
    const int b = (bq0 + q) / QLEN;
    // head-major base: [b][h][key][32], thread reads 8 dims at dp*8
    const unsigned short* vbase = vb + (size_t)(b * 8 + h) * NUM_KEYS * 32 + dp * 8;

    float acc[8];
#pragma unroll
    for (int d = 0; d < 8; ++d) acc[d] = 0.f;

#pragma unroll
    for (int l = 0; l < LEVELS; ++l) {
        const int Hl = c_LH[l];
        const int Wl = c_LW[l];
        const int s0 = c_LS[l];
#pragma unroll 2
        for (int p = 0; p < POINTS; ++p) {
            const int t2 = h * 16 + l * 4 + p;
            const float x = s_x[q][t2];
            const float y = s_y[q][t2];
            const float w = s_w[q][t2];
            const float x0f = floorf(x);
            const float y0f = floorf(y);
            const float wx = x - x0f;
            const float wy = y - y0f;
            const int x0 = (int)x0f;
            const int y0 = (int)y0f;
            const float mx0 = ((unsigned)x0 < (unsigned)Wl) ? 1.f : 0.f;
            const float mx1 = ((unsigned)(x0 + 1) < (unsigned)Wl) ? 1.f : 0.f;
            const float my0 = ((unsigned)y0 < (unsigned)Hl) ? 1.f : 0.f;
            const float my1 = ((unsigned)(y0 + 1) < (unsigned)Hl) ? 1.f : 0.f;
            const int xc0 = min(max(x0, 0), Wl - 1);
            const int xc1 = min(max(x0 + 1, 0), Wl - 1);
            const int yc0 = min(max(y0, 0), Hl - 1);
            const int yc1 = min(max(y0 + 1, 0), Hl - 1);
            const float a00 = w * (1.f - wx) * (1.f - wy) * mx0 * my0;
            const float a01 = w * wx * (1.f - wy) * mx1 * my0;
            const float a10 = w * (1.f - wx) * wy * mx0 * my1;
            const float a11 = w * wx * wy * mx1 * my1;
            const size_t k00 = (size_t)(s0 + yc0 * Wl + xc0) * 32;
            const size_t k01 = (size_t)(s0 + yc0 * Wl + xc1) * 32;
            const size_t k10 = (size_t)(s0 + yc1 * Wl + xc0) * 32;
            const size_t k11 = (size_t)(s0 + yc1 * Wl + xc1) * 32;
            const uint4 r00 = *(const uint4*)(vbase + k00);
            const uint4 r01 = *(const uint4*)(vbase + k01);
            const uint4 r10 = *(const uint4*)(vbase + k10);
            const uint4 r11 = *(const uint4*)(vbase + k11);
            const unsigned int w00[4] = {r00.x, r00.y, r00.z, r00.w};
            const unsigned int w01[4] = {r01.x, r01.y, r01.z, r01.w};
            const unsigned int w10[4] = {r10.x, r10.y, r10.z, r10.w};
            const unsigned int w11[4] = {r11.x, r11.y, r11.z, r11.w};
#pragma unroll
            for (int i = 0; i < 4; ++i) {
                const float v00l = bf2f(w00[i] & 0xffffu), v00h = bf2f(w00[i] >> 16);
                const float v01l = bf2f(w01[i] & 0xffffu), v01h = bf2f(w01[i] >> 16);
                const float v10l = bf2f(w10[i] & 0xffffu), v10h = bf2f(w10[i] >> 16);
                const float v11l = bf2f(w11[i] & 0xffffu), v11h = bf2f(w11[i] >> 16);
                acc[i * 2 + 0] = fmaf(a00, v00l, fmaf(a01, v01l, fmaf(a10, v10l, fmaf(a11, v11l, acc[i * 2 + 0]))));
                acc[i * 2 + 1] = fmaf(a00, v00h, fmaf(a01, v01h, fmaf(a10, v10h, fmaf(a11, v11h, acc[i * 2 + 1]))));
            }
        }
    }

    // write sampled features to LDS (bf16, XOR-swizzled: byte(row,cb) =
    // row*512 + (cb ^ ((row&7)<<4)), same involution on write and read)
    {
        unsigned short o[8];
#pragma unroll
        for (int d = 0; d < 8; ++d) o[d] = f2bf(acc[d]);
        const int cb = (h * 32 + dp * 8) * 2;
        *(uint4*)((char*)s_o + q * 512 + (cb ^ ((q & 7) << 4))) = *(uint4*)o;
    }
    __syncthreads();

    // ---- fused output projection: out[8][256] = s_o[0:8] @ Wo^T + b_out ----
    // 4 waves x 64-col strips; rows 8..15 of s_o are garbage -> acc quads 2,3
    // discarded (MFMA row independence).
    {
        const int wv = tid >> 6;
        const int lane = tid & 63;
        const int ln = lane & 15;
        const int quad = lane >> 4;
        const int n0 = wv * 64;

        ffrag oacc[4];
#pragma unroll
        for (int j = 0; j < 4; ++j) oacc[j] = (ffrag){0.f, 0.f, 0.f, 0.f};
#pragma unroll
        for (int ks = 0; ks < 8; ++ks) {
            const int cbk = (ks * 64 + quad * 16) ^ ((ln & 7) << 4);
            const bfrag af = *(const bfrag*)((const char*)s_o + ln * 512 + cbk);
#pragma unroll
            for (int j = 0; j < 4; ++j) {
                const bfrag bf = *(const bfrag*)(Wo + (size_t)(n0 + j * 16 + ln) * 256 + ks * 32 + quad * 8);
                oacc[j] = __builtin_amdgcn_mfma_f32_16x16x32_bf16(af, bf, oacc[j], 0, 0, 0);
            }
        }
        // store rows 0..7 (quads 0,1): row = quad*4 + r, col = n0 + j*16 + ln
        if (quad < 2) {
#pragma unroll
            for (int j = 0; j < 4; ++j) {
                const int col = n0 + j * 16 + ln;
                const float bb = b_out[col];
#pragma unroll
                for (int r = 0; r < 4; ++r)
                    out[(size_t)(bq0 + quad * 4 + r) * 256 + col] = oacc[j][r] + bb;
            }
        }
    }
}

// ---------------------------------------------------------------------------
extern "C" void kernel_launch(void* const* d_in, const int* in_sizes, int n_in,
                              void* d_out, int out_size, void* d_ws, size_t ws_size,
                              hipStream_t stream) {
    const float* query  = (const float*)d_in[0];
    const float* rp     = (const float*)d_in[1];
    const float* value  = (const float*)d_in[2];
    const float* W_off  = (const float*)d_in[5];
    const float* b_off  = (const float*)d_in[6];
    const float* W_attn = (const float*)d_in[7];
    const float* b_attn = (const float*)d_in[8];
    const float* W_val  = (const float*)d_in[9];
    const float* b_val  = (const float*)d_in[10];
    const float* W_out  = (const float*)d_in[11];
    const float* b_out  = (const float*)d_in[12];
    float* out = (float*)d_out;

    // workspace layout
    char* w = (char*)d_ws;
    unsigned short* ws_vb = (unsigned short*)w;                 // [b][h][key][32] bf16
    w += (size_t)MROWS_V * 256 * 2;
    float* ws_offattn = (float*)w;                              // BQ*384 f32
    w += (size_t)BQ * 384 * 4;
    unsigned short* ws_msda = (unsigned short*)w;               // (unused, kept for layout)
    w += (size_t)BQ * 256 * 2;
    unsigned short* ws_Wv = (unsigned short*)w;  w += 256 * 256 * 2;   // [n][k]
    unsigned short* ws_Woa = (unsigned short*)w; w += 384 * 256 * 2;   // [n][k]
    unsigned short* ws_Wo = (unsigned short*)w;  w += 256 * 256 * 2;   // [n][k]
    float* ws_boa = (float*)w;                                   // 384 f32
    (void)ws_msda;

    // 0. merged weight prep (bf16, transposed) + bias concat
    prep_kernel<<<898, 256, 0, stream>>>(W_val, W_off, W_attn, W_out,
                                         b_off, b_attn, ws_Wv, ws_Woa, ws_Wo, ws_boa);

    // 1. value projection -> bf16 head-major (M=106352, N=256), 512-thr blocks
    gemm_val_stream<<<VBLOCKS, 512, 0, stream>>>(value, ws_Wv, b_val, ws_vb);

    // 2. fused offset+attn projection -> fp32 (M=7200, N=384)
    {
        dim3 grid((BQ + 63) / 64, 3);
        gemm_mfma<float, float><<<grid, 256, 0, stream>>>(
            query, ws_Woa, ws_boa, ws_offattn, BQ, 384);
    }
    // 3. softmax + locations + sampling + output projection -> d_out
    msda_fused_kernel<<<BQ / 8, 256, 0, stream>>>(ws_offattn, rp, ws_vb,
                                                  ws_Wo, b_out, out);
}

// Round 10
// 244.652 us; speedup vs baseline: 1.0318x; 1.0198x over previous
//
#include <hip/hip_runtime.h>
#include <hip/hip_bf16.h>
#include <math.h>
#include <type_traits>

// Problem constants (fixed by setup_inputs)
#define BATCH 8
#define QLEN 900
#define HEADS 8
#define LEVELS 4
#define POINTS 4
#define NUM_KEYS 13294
#define BQ (BATCH * QLEN)          // 7200
#define MROWS_V (BATCH * NUM_KEYS) // 106352
#define VTILES (MROWS_V / 16)      // 6647 16-row tiles (exact)
#define VBLOCKS 512
#define TPB 13                     // ceil(6647/512)

__constant__ const int c_LH[4] = {100, 50, 25, 13};
__constant__ const int c_LW[4] = {100, 50, 25, 13};
__constant__ const int c_LS[4] = {0, 10000, 12500, 13125};

typedef __attribute__((ext_vector_type(8))) short bfrag;   // 8 bf16
typedef __attribute__((ext_vector_type(4))) float ffrag;   // 4 fp32 acc

static __device__ __forceinline__ unsigned short f2bf(float f) {
    __hip_bfloat16 h = __float2bfloat16(f);
    return *(unsigned short*)&h;
}
static __device__ __forceinline__ float bf2f(unsigned int u16) {
    unsigned int v = u16 << 16;
    float f;
    __builtin_memcpy(&f, &v, 4);
    return f;
}
static __device__ __forceinline__ unsigned long long pack4bf(float4 v) {
    return (unsigned long long)f2bf(v.x)
         | ((unsigned long long)f2bf(v.y) << 16)
         | ((unsigned long long)f2bf(v.z) << 32)
         | ((unsigned long long)f2bf(v.w) << 48);
}

// ---------------------------------------------------------------------------
// Merged prep: cast+transpose all three weight matrices to bf16 [n][k],
// concat off/attn biases. One launch instead of five.
// ---------------------------------------------------------------------------
__global__ __launch_bounds__(256)
void prep_kernel(const float* __restrict__ W_val, const float* __restrict__ W_off,
                 const float* __restrict__ W_attn, const float* __restrict__ W_out,
                 const float* __restrict__ b_off, const float* __restrict__ b_attn,
                 unsigned short* __restrict__ Wv, unsigned short* __restrict__ Woa,
                 unsigned short* __restrict__ Wo, float* __restrict__ boa) {
    const int id = blockIdx.x * 256 + threadIdx.x;
    if (id < 65536) {
        const int n = id >> 8, k = id & 255;
        Wv[id] = f2bf(W_val[k * 256 + n]);
    } else if (id < 131072) {
        const int t = id - 65536;
        const int n = t >> 8, k = t & 255;
        Woa[t] = f2bf(W_off[k * 256 + n]);
    } else if (id < 163840) {
        const int t = id - 131072;
        const int n = t >> 8, k = t & 255;       // n in 0..127
        Woa[65536 + t] = f2bf(W_attn[k * 128 + n]);
    } else if (id < 229376) {
        const int t = id - 163840;
        const int n = t >> 8, k = t & 255;
        Wo[t] = f2bf(W_out[k * 256 + n]);
    } else if (id < 229760) {
        const int t = id - 229376;
        boa[t] = (t < 256) ? b_off[t] : b_attn[t - 256];
    }
}

// ---------------------------------------------------------------------------
// Value-projection GEMM v7: C = bf16(A @ Wv + bias), HEAD-MAJOR output
// [b][h][key][32]. 512 thr / 8 waves x 32 cols, b[2][8]=64 VGPR/wave,
// __launch_bounds__(512,4). Per-instruction-contiguous staging loads,
// f32->bf16 once at staging, 3-deep 8KB LDS ring, named L0/L1 reg sets
// (rule #20), one raw s_barrier + lgkmcnt(0) per tile, XOR-swizzled LDS.
// FROZEN since round 7.
// ---------------------------------------------------------------------------
#define VSTEP(T, LREG)                                                        \
  do {                                                                        \
    const char* abuf = (const char*)&Abuf[0][0] + rb * 8192;                  \
    ffrag acc[2];                                                             \
    _Pragma("unroll")                                                         \
    for (int j_ = 0; j_ < 2; ++j_) acc[j_] = (ffrag){0.f, 0.f, 0.f, 0.f};     \
    _Pragma("unroll")                                                         \
    for (int ks_ = 0; ks_ < 8; ++ks_) {                                       \
      const int ub_ = (ks_ * 64 + quad * 16) ^ ((ln & 7) << 4);               \
      const bfrag af_ = *(const bfrag*)(abuf + ln * 512 + ub_);               \
      _Pragma("unroll")                                                       \
      for (int j_ = 0; j_ < 2; ++j_)                                          \
        acc[j_] = __builtin_amdgcn_mfma_f32_16x16x32_bf16(af_, b[j_][ks_],    \
                                                          acc[j_], 0, 0, 0); \
    }                                                                         \
    if ((T) + 1 < t1) {                                                       \
      const int wb_ = (rb + 1 == 3) ? 0 : rb + 1;                             \
      char* dbuf_ = (char*)&Abuf[0][0] + wb_ * 8192;                          \
      _Pragma("unroll")                                                       \
      for (int i_ = 0; i_ < 2; ++i_)                                          \
        *(unsigned long long*)(dbuf_ + dsoff[i_]) = pack4bf(LREG[i_]);        \
      if ((T) + 3 < t1) {                                                     \
        const float4* ap_ = Af4 + (size_t)((T) + 3) * 1024 + tid;             \
        _Pragma("unroll")                                                     \
        for (int i_ = 0; i_ < 2; ++i_) LREG[i_] = ap_[i_ * 512];              \
      }                                                                       \
    }                                                                         \
    const int rowb_ = (T) * 16 + quad * 4;                                    \
    _Pragma("unroll")                                                         \
    for (int r_ = 0; r_ < 4; ++r_) {                                          \
      const unsigned row_ = rowb_ + r_;                                       \
      const unsigned bb_ = row_ / NUM_KEYS;                                   \
      const unsigned key_ = row_ - bb_ * NUM_KEYS;                            \
      _Pragma("unroll")                                                       \
      for (int j_ = 0; j_ < 2; ++j_) {                                        \
        const int col_ = n0 + j_ * 16 + ln;                                   \
        const int h_ = col_ >> 5, d_ = col_ & 31;                             \
        C[((size_t)(bb_ * 8 + h_) * NUM_KEYS + key_) * 32 + d_] =             \
            f2bf(acc[j_][r_] + bj[j_]);                                       \
      }                                                                       \
    }                                                                         \
    asm volatile("s_waitcnt lgkmcnt(0)" ::: "memory");                        \
    __builtin_amdgcn_s_barrier();                                             \
    rb = (rb + 1 == 3) ? 0 : rb + 1;                                          \
  } while (0)

__global__ __launch_bounds__(512, 4)
void gemm_val_stream(const float* __restrict__ A, const unsigned short* __restrict__ WT,
                     const float* __restrict__ bias, unsigned short* __restrict__ C) {
    __shared__ __align__(16) unsigned short Abuf[3][16 * 256];  // 3 x 8KB bf16 tiles
    const int tid = threadIdx.x;
    const int wave = tid >> 6;
    const int lane = tid & 63;
    const int ln = lane & 15;
    const int quad = lane >> 4;
    const int n0 = wave * 32;           // wave covers one 32-col head slice

    // persistent B fragments: 2 n-tiles x 8 k-steps (64 VGPR)
    bfrag b[2][8];
#pragma unroll
    for (int j = 0; j < 2; ++j) {
        const unsigned short* bp = WT + (size_t)(n0 + j * 16 + ln) * 256 + quad * 8;
#pragma unroll
        for (int ks = 0; ks < 8; ++ks) b[j][ks] = *(const bfrag*)(bp + ks * 32);
    }
    float bj[2];
#pragma unroll
    for (int j = 0; j < 2; ++j) bj[j] = bias[n0 + j * 16 + ln];

    const int t0 = blockIdx.x * TPB;
    const int t1 = min(t0 + TPB, VTILES);
    if (t0 >= t1) return;

    // staging destination offsets: instr i covers float4 index f = i*512+tid
    int dsoff[2];
#pragma unroll
    for (int i = 0; i < 2; ++i) {
        const int f = i * 512 + tid;
        const int r = f >> 6;
        const int cb = (f & 63) * 8;
        dsoff[i] = r * 512 + (cb ^ ((r & 7) << 4));
    }

    const float4* Af4 = (const float4*)A;

    // prologue: stage tile t0 directly, then fill the 2-deep NAMED register
    // pipeline: t0+1 -> L0, t0+2 -> L1.
    float4 L0[2], L1[2];
    {
        const float4* ap = Af4 + (size_t)t0 * 1024 + tid;
        float4 P[2];
#pragma unroll
        for (int i = 0; i < 2; ++i) P[i] = ap[i * 512];
#pragma unroll
        for (int i = 0; i < 2; ++i)
            *(unsigned long long*)((char*)&Abuf[0][0] + dsoff[i]) = pack4bf(P[i]);
    }
    if (t0 + 1 < t1) {
        const float4* ap = Af4 + (size_t)(t0 + 1) * 1024 + tid;
#pragma unroll
        for (int i = 0; i < 2; ++i) L0[i] = ap[i * 512];
    }
    if (t0 + 2 < t1) {
        const float4* ap = Af4 + (size_t)(t0 + 2) * 1024 + tid;
#pragma unroll
        for (int i = 0; i < 2; ++i) L1[i] = ap[i * 512];
    }
    asm volatile("s_waitcnt lgkmcnt(0)" ::: "memory");
    __builtin_amdgcn_s_barrier();

    int rb = 0;
    int t = t0;
    while (t + 1 < t1) {
        VSTEP(t, L0);
        VSTEP(t + 1, L1);
        t += 2;
    }
    if (t < t1) VSTEP(t, L0);
}

// ---------------------------------------------------------------------------
// bf16-MFMA GEMM: C[M,N] = bf16(A[M,256]) @ WT^T + bias.
// WT is [N][256] bf16 (pre-transposed). BM=64, BN=128, BK=64, 256 thr = 4 waves.
// Used for the offattn GEMM and the (re-unfused) out-projection.
// ---------------------------------------------------------------------------
#define GST 72

template <typename AT, typename CT>
__global__ __launch_bounds__(256)
void gemm_mfma(const AT* __restrict__ A, const unsigned short* __restrict__ WT,
               const float* __restrict__ bias, CT* __restrict__ C,
               int M, int ldc) {
    __shared__ unsigned short As[64 * GST];
    __shared__ unsigned short Bs[128 * GST];
    const int tid = threadIdx.x;
    const int wave = tid >> 6;
    const int lane = tid & 63;
    const int ln = lane & 15;
    const int quad = lane >> 4;
    const int m0 = blockIdx.x * 64;
    const int n0 = blockIdx.y * 128;

    ffrag acc[8];
#pragma unroll
    for (int j = 0; j < 8; ++j) acc[j] = (ffrag){0.f, 0.f, 0.f, 0.f};

    const int ar = tid >> 2;            // A row in tile (0..63)
    const int akc = (tid & 3) * 16;     // A k-chunk (16 elems)
    const int brow = tid >> 1;          // B col in tile (0..127)
    const int bkc = (tid & 1) * 32;     // B k-chunk (32 elems)
    const bool a_ok = (m0 + ar) < M;
    const AT* a_src = A + (size_t)(m0 + ar) * 256 + akc;
    const unsigned short* b_src = WT + (size_t)(n0 + brow) * 256 + bkc;

    for (int k0 = 0; k0 < 256; k0 += 64) {
        // ---- stage A (64 x 64, -> bf16) ----
        unsigned short* adst = &As[ar * GST + akc];
        if constexpr (std::is_same<AT, float>::value) {
            float4 f0, f1, f2, f3;
            if (a_ok) {
                const float4* p = (const float4*)(a_src + k0);
                f0 = p[0]; f1 = p[1]; f2 = p[2]; f3 = p[3];
            } else {
                f0 = make_float4(0.f, 0.f, 0.f, 0.f);
                f1 = f0; f2 = f0; f3 = f0;
            }
            float v[16] = {f0.x, f0.y, f0.z, f0.w, f1.x, f1.y, f1.z, f1.w,
                           f2.x, f2.y, f2.z, f2.w, f3.x, f3.y, f3.z, f3.w};
            unsigned short u[16];
#pragma unroll
            for (int i = 0; i < 16; ++i) u[i] = f2bf(v[i]);
            ((uint4*)adst)[0] = ((uint4*)u)[0];
            ((uint4*)adst)[1] = ((uint4*)u)[1];
        } else {
            uint4 u0, u1;
            if (a_ok) {
                const uint4* p = (const uint4*)(a_src + k0);
                u0 = p[0]; u1 = p[1];
            } else {
                u0 = make_uint4(0, 0, 0, 0);
                u1 = u0;
            }
            ((uint4*)adst)[0] = u0;
            ((uint4*)adst)[1] = u1;
        }
        // ---- stage B (128 cols x 64 k) ----
        {
            const uint4* src = (const uint4*)(b_src + k0);
            uint4* dst = (uint4*)&Bs[brow * GST + bkc];
#pragma unroll
            for (int i = 0; i < 4; ++i) dst[i] = src[i];
        }
        __syncthreads();

#pragma unroll
        for (int ks = 0; ks < 2; ++ks) {
            const int koff = ks * 32 + quad * 8;
            bfrag af = *(const bfrag*)&As[(wave * 16 + ln) * GST + koff];
#pragma unroll
            for (int j = 0; j < 8; ++j) {
                bfrag bf = *(const bfrag*)&Bs[(j * 16 + ln) * GST + koff];
                acc[j] = __builtin_amdgcn_mfma_f32_16x16x32_bf16(af, bf, acc[j], 0, 0, 0);
            }
        }
        __syncthreads();
    }

    // epilogue: row = m0 + wave*16 + quad*4 + r, col = n0 + j*16 + ln
#pragma unroll
    for (int j = 0; j < 8; ++j) {
        const int col = n0 + j * 16 + ln;
        const float bb = bias[col];
#pragma unroll
        for (int r = 0; r < 4; ++r) {
            const int row = m0 + wave * 16 + quad * 4 + r;
            if (row < M) {
                const float v = acc[j][r] + bb;
                if constexpr (std::is_same<CT, unsigned short>::value) {
                    C[(size_t)row * ldc + col] = f2bf(v);
                } else {
                    C[(size_t)row * ldc + col] = v;
                }
            }
        }
    }
}

// ---------------------------------------------------------------------------
// Softmax + locations + bilinear sampling over HEAD-MAJOR bf16 values
// (vb layout [b][h][key][32]).
// Round-10: HEAD-HALF block remap for gather L2 footprint. Block = 16 queries
// x 4 heads (one head-half) x 4 dp = 256 threads. Rationale: all 900 blocks
// are co-resident; with 8q x 8h blocks each XCD's instantaneous gather
// working set was ~2 batches x 8 heads = 13.6MB vs 4MB L2 -> ~0% hit (round-5
// counters: FETCH ~= full 290MB logical traffic; round-9 batch-swizzle only
// -3us). Head-half blocks + (head-half, batch)-major chunked XCD swizzle
// halve the per-XCD footprint to ~6.8MB -> L2 absorbs ~half the 4.4x reuse.
// Out-projection un-fused again (a block no longer holds all 256 dims;
// round-8 showed fusion was neutral anyway). Gather arithmetic unchanged.
// ---------------------------------------------------------------------------
__global__ __launch_bounds__(256, 4)
void msda_sample_kernel(const float* __restrict__ offattn,  // [BQ][384]
                        const float* __restrict__ rp,
                        const unsigned short* __restrict__ vb,  // [b][h][key][32] bf16
                        unsigned short* __restrict__ outb) {    // (bq,256) bf16
    // bijective XCD chunk swizzle (m204: nwg=900, q=112, r=4), then decode
    // wgid in (head-half, batch)-major order: hh = wgid/450, pos = wgid%450.
    const int orig = blockIdx.x;
    const int xcd = orig & 7;
    const int idx = orig >> 3;
    const int wgid = (xcd < 4) ? (xcd * 113 + idx) : (452 + (xcd - 4) * 112 + idx);
    const int hh = wgid / 450;
    const int pos = wgid - hh * 450;
    const int bq0 = pos * 16;
    const int hb = hh * 4;              // head base for this block
    const int tid = threadIdx.x;

    __shared__ float s_w[16][64];
    __shared__ float s_x[16][64];
    __shared__ float s_y[16][64];

    // load attn logits: 16 q x (4 heads x 16 lp) = 1024 entries
#pragma unroll
    for (int i = 0; i < 4; ++i) {
        const int e = i * 256 + tid;
        const int q = e >> 6, t = e & 63;
        const int h = hb + (t >> 4), lp = t & 15;
        s_w[q][t] = offattn[(size_t)(bq0 + q) * 384 + 256 + h * 16 + lp];
    }
    __syncthreads();

    // softmax per (q, h4): 64 threads, 16 logits each
    if (tid < 64) {
        const int q = tid >> 2, h4 = tid & 3;
        float m = -1e30f;
#pragma unroll
        for (int i = 0; i < 16; ++i) m = fmaxf(m, s_w[q][h4 * 16 + i]);
        float e[16];
        float ssum = 0.f;
#pragma unroll
        for (int i = 0; i < 16; ++i) {
            e[i] = expf(s_w[q][h4 * 16 + i] - m);
            ssum += e[i];
        }
        const float inv = 1.f / ssum;
#pragma unroll
        for (int i = 0; i < 16; ++i) s_w[q][h4 * 16 + i] = e[i] * inv;
    }

    // sampling coordinates (16 q x 64)
#pragma unroll
    for (int i = 0; i < 4; ++i) {
        const int e = i * 256 + tid;
        const int q = e >> 6, t = e & 63;
        const int h = hb + (t >> 4), l = (t >> 2) & 3, p = t & 3;
        const int bq = bq0 + q;
        const float2 off = *(const float2*)(offattn + (size_t)bq * 384 + h * 32 + l * 8 + p * 2);
        const float Wl = (float)c_LW[l];
        const float Hl = (float)c_LH[l];
        const float rx = rp[((size_t)bq * 4 + l) * 2 + 0];
        const float ry = rp[((size_t)bq * 4 + l) * 2 + 1];
        s_x[q][t] = (rx + off.x / Wl) * Wl - 0.5f;   // reference op order
        s_y[q][t] = (ry + off.y / Hl) * Hl - 0.5f;
    }
    __syncthreads();

    const int q = tid >> 4;
    const int s = tid & 15;
    const int h4 = s >> 2;
    const int dp = s & 3;
    const int bq = bq0 + q;
    const int b = bq / QLEN;
    const int h = hb + h4;
    // head-major base: [b][h][key][32], thread reads 8 dims at dp*8
    const unsigned short* vbase = vb + (size_t)(b * 8 + h) * NUM_KEYS * 32 + dp * 8;

    float acc[8];
#pragma unroll
    for (int d = 0; d < 8; ++d) acc[d] = 0.f;

#pragma unroll
    for (int l = 0; l < LEVELS; ++l) {
        const int Hl = c_LH[l];
        const int Wl = c_LW[l];
        const int s0 = c_LS[l];
#pragma unroll 2
        for (int p = 0; p < POINTS; ++p) {
            const int t2 = h4 * 16 + l * 4 + p;
            const float x = s_x[q][t2];
            const float y = s_y[q][t2];
            const float w = s_w[q][t2];
            const float x0f = floorf(x);
            const float y0f = floorf(y);
            const float wx = x - x0f;
            const float wy = y - y0f;
            const int x0 = (int)x0f;
            const int y0 = (int)y0f;
            const float mx0 = ((unsigned)x0 < (unsigned)Wl) ? 1.f : 0.f;
            const float mx1 = ((unsigned)(x0 + 1) < (unsigned)Wl) ? 1.f : 0.f;
            const float my0 = ((unsigned)y0 < (unsigned)Hl) ? 1.f : 0.f;
            const float my1 = ((unsigned)(y0 + 1) < (unsigned)Hl) ? 1.f : 0.f;
            const int xc0 = min(max(x0, 0), Wl - 1);
            const int xc1 = min(max(x0 + 1, 0), Wl - 1);
            const int yc0 = min(max(y0, 0), Hl - 1);
            const int yc1 = min(max(y0 + 1, 0), Hl - 1);
            const float a00 = w * (1.f - wx) * (1.f - wy) * mx0 * my0;
            const float a01 = w * wx * (1.f - wy) * mx1 * my0;
            const float a10 = w * (1.f - wx) * wy * mx0 * my1;
            const float a11 = w * wx * wy * mx1 * my1;
            const size_t k00 = (size_t)(s0 + yc0 * Wl + xc0) * 32;
            const size_t k01 = (size_t)(s0 + yc0 * Wl + xc1) * 32;
            const size_t k10 = (size_t)(s0 + yc1 * Wl + xc0) * 32;
            const size_t k11 = (size_t)(s0 + yc1 * Wl + xc1) * 32;
            const uint4 r00 = *(const uint4*)(vbase + k00);
            const uint4 r01 = *(const uint4*)(vbase + k01);
            const uint4 r10 = *(const uint4*)(vbase + k10);
            const uint4 r11 = *(const uint4*)(vbase + k11);
            const unsigned int w00[4] = {r00.x, r00.y, r00.z, r00.w};
            const unsigned int w01[4] = {r01.x, r01.y, r01.z, r01.w};
            const unsigned int w10[4] = {r10.x, r10.y, r10.z, r10.w};
            const unsigned int w11[4] = {r11.x, r11.y, r11.z, r11.w};
#pragma unroll
            for (int i = 0; i < 4; ++i) {
                const float v00l = bf2f(w00[i] & 0xffffu), v00h = bf2f(w00[i] >> 16);
                const float v01l = bf2f(w01[i] & 0xffffu), v01h = bf2f(w01[i] >> 16);
                const float v10l = bf2f(w10[i] & 0xffffu), v10h = bf2f(w10[i] >> 16);
                const float v11l = bf2f(w11[i] & 0xffffu), v11h = bf2f(w11[i] >> 16);
                acc[i * 2 + 0] = fmaf(a00, v00l, fmaf(a01, v01l, fmaf(a10, v10l, fmaf(a11, v11l, acc[i * 2 + 0]))));
                acc[i * 2 + 1] = fmaf(a00, v00h, fmaf(a01, v01h, fmaf(a10, v10h, fmaf(a11, v11h, acc[i * 2 + 1]))));
            }
        }
    }

    unsigned short o[8];
#pragma unroll
    for (int d = 0; d < 8; ++d) o[d] = f2bf(acc[d]);
    *(uint4*)(outb + (size_t)bq * 256 + h * 32 + dp * 8) = *(uint4*)o;
}

// ---------------------------------------------------------------------------
extern "C" void kernel_launch(void* const* d_in, const int* in_sizes, int n_in,
                              void* d_out, int out_size, void* d_ws, size_t ws_size,
                              hipStream_t stream) {
    const float* query  = (const float*)d_in[0];
    const float* rp     = (const float*)d_in[1];
    const float* value  = (const float*)d_in[2];
    const float* W_off  = (const float*)d_in[5];
    const float* b_off  = (const float*)d_in[6];
    const float* W_attn = (const float*)d_in[7];
    const float* b_attn = (const float*)d_in[8];
    const float* W_val  = (const float*)d_in[9];
    const float* b_val  = (const float*)d_in[10];
    const float* W_out  = (const float*)d_in[11];
    const float* b_out  = (const float*)d_in[12];
    float* out = (float*)d_out;

    // workspace layout
    char* w = (char*)d_ws;
    unsigned short* ws_vb = (unsigned short*)w;                 // [b][h][key][32] bf16
    w += (size_t)MROWS_V * 256 * 2;
    float* ws_offattn = (float*)w;                              // BQ*384 f32
    w += (size_t)BQ * 384 * 4;
    unsigned short* ws_msda = (unsigned short*)w;               // BQ*256 bf16
    w += (size_t)BQ * 256 * 2;
    unsigned short* ws_Wv = (unsigned short*)w;  w += 256 * 256 * 2;   // [n][k]
    unsigned short* ws_Woa = (unsigned short*)w; w += 384 * 256 * 2;   // [n][k]
    unsigned short* ws_Wo = (unsigned short*)w;  w += 256 * 256 * 2;   // [n][k]
    float* ws_boa = (float*)w;                                   // 384 f32

    // 0. merged weight prep (bf16, transposed) + bias concat
    prep_kernel<<<898, 256, 0, stream>>>(W_val, W_off, W_attn, W_out,
                                         b_off, b_attn, ws_Wv, ws_Woa, ws_Wo, ws_boa);

    // 1. value projection -> bf16 head-major (M=106352, N=256), 512-thr blocks
    gemm_val_stream<<<VBLOCKS, 512, 0, stream>>>(value, ws_Wv, b_val, ws_vb);

    // 2. fused offset+attn projection -> fp32 (M=7200, N=384)
    {
        dim3 grid((BQ + 63) / 64, 3);
        gemm_mfma<float, float><<<grid, 256, 0, stream>>>(
            query, ws_Woa, ws_boa, ws_offattn, BQ, 384);
    }
    // 3. softmax + locations + sampling (16q x 4h blocks, XCD-chunked)
    msda_sample_kernel<<<900, 256, 0, stream>>>(ws_offattn, rp, ws_vb, ws_msda);

    // 4. output projection -> d_out fp32 (M=7200, N=256)
    {
        dim3 grid((BQ + 63) / 64, 2);
        gemm_mfma<unsigned short, float><<<grid, 256, 0, stream>>>(
            ws_msda, ws_Wo, b_out, out, BQ, 256);
    }
}